// Round 5
// baseline (321.401 us; speedup 1.0000x reference)
//
#include <hip/hip_runtime.h>
#include <stdint.h>

// ReconBlock: 3-axis 3-tap submanifold conv (gathered neighbors) + BN(inference)
// + sigmoid per branch, branches summed, gated by input features.
// fp32 in/out; compute via bf16 MFMA (16x16x32).
//
// R5 = R4 minus nontemporal stores (bisect: R4 passed first launch but diverged
// after graph replays; nt-store is the only memory-semantics delta vs R3 which
// passed this harness flow).
//  - W fragments in LDS (ds_read_b128 per MFMA) -> ~72 VGPRs freed so a tile's
//    20 VMEM loads can all be outstanding (R3 was load-serialized: 1400cyc/tile
//    with only ~450 issue-busy).
//  - Branchless gathers: clamp address to the (L1-hot) self row, zero the bf16
//    fragment with v_and. No exec-mask branches in the hot loop.
//  - All neighbor indices loaded up-front.

typedef __attribute__((ext_vector_type(8))) __bf16 bf16x8;
typedef __attribute__((ext_vector_type(8))) unsigned short u16x8;
typedef __attribute__((ext_vector_type(4))) float f32x4;
typedef __attribute__((ext_vector_type(2))) float f32x2;
typedef __attribute__((ext_vector_type(4))) unsigned u32x4;

constexpr int NVOX    = 1000000;
constexpr int NTILES  = NVOX / 16;                  // 62500
constexpr int TPW     = 2;                          // tiles per wave
constexpr int WPB     = 4;                          // waves per block
constexpr int NWAVES  = (NTILES + TPW - 1) / TPW;   // 31250
constexpr int NBLOCKS = (NWAVES + WPB - 1) / WPB;   // 7813
constexpr float LOG2E = 1.4426950408889634f;

// ws layout: bf16 W frags [18][64][8] (18432 B), then A[3][32], B[3][32] fp32
constexpr int WS_WELEMS = 18 * 64 * 8;              // 9216 bf16 elems

__global__ __launch_bounds__(256) void prep_kernel(
    const float* __restrict__ Wt,    // [3][3][32][32]
    const float* __restrict__ gma, const float* __restrict__ bta,
    const float* __restrict__ mea, const float* __restrict__ var,
    unsigned short* __restrict__ wsW, float* __restrict__ wsA,
    float* __restrict__ wsB)
{
    int tid = blockIdx.x * 256 + threadIdx.x;
    if (tid < WS_WELEMS) {
        int f    = tid >> 9;          // fragment id = (br*3+t)*2+h
        int rem  = tid & 511;
        int lane = rem >> 3;
        int j    = rem & 7;
        int br = f / 6, t = (f >> 1) % 3, h = f & 1;
        int n = lane & 15, quad = lane >> 4;
        // B[k=quad*8+j][col]; col interleave: half h = original channel 2n+h
        float w = Wt[((br * 3 + t) * 32 + quad * 8 + j) * 32 + 2 * n + h];
        union { float f; unsigned u; } c; c.f = w;
        wsW[(f * 64 + lane) * 8 + j] = (unsigned short)((c.u + 0x8000u) >> 16);
    } else if (tid < WS_WELEMS + 96) {
        int i = tid - WS_WELEMS;      // br*32 + c
        float s = gma[i] * __frsqrt_rn(var[i] + 1e-5f);
        wsA[i] = -s * LOG2E;
        wsB[i] = (mea[i] * s - bta[i]) * LOG2E;
    }
}

__device__ __forceinline__ unsigned pack_bf(float a, float b) {
    union { float f; unsigned u; } ca, cb; ca.f = a; cb.f = b;
    // d = hi16(a+0x8000) | hi16(b+0x8000)<<16  (one v_perm)
    return __builtin_amdgcn_perm(cb.u + 0x8000u, ca.u + 0x8000u, 0x07060302u);
}
// convert 8 fp32 -> bf16x8, zeroed when !act (branchless)
__device__ __forceinline__ bf16x8 cvt_mask(f32x4 lo, f32x4 hi, bool act) {
    unsigned m = act ? 0xffffffffu : 0u;
    union { unsigned u[4]; bf16x8 v; } r;
    r.u[0] = pack_bf(lo[0], lo[1]) & m; r.u[1] = pack_bf(lo[2], lo[3]) & m;
    r.u[2] = pack_bf(hi[0], hi[1]) & m; r.u[3] = pack_bf(hi[2], hi[3]) & m;
    return r.v;
}

__global__ __launch_bounds__(256, 3) void recon_kernel(
    const float*          __restrict__ feat,   // [N][32]
    const int*            __restrict__ nprev,  // [3][N]
    const int*            __restrict__ nnext,  // [3][N]
    const unsigned short* __restrict__ wsW,    // [18][64][8] bf16
    const float*          __restrict__ wsA,    // [3][32]
    const float*          __restrict__ wsB,    // [3][32]
    float*                __restrict__ out)    // [N][32]
{
    __shared__ unsigned short sW[WS_WELEMS];   // 18432 B

    // ---- cooperative W copy ws -> LDS (1152 x 16 B chunks)
    {
        const u32x4* src = (const u32x4*)wsW;
        u32x4*       dst = (u32x4*)sW;
        #pragma unroll
        for (int k = 0; k < 5; ++k) {
            int i = threadIdx.x + k * 256;
            if (i < WS_WELEMS / 8) dst[i] = src[i];
        }
    }
    __syncthreads();

    const int lane = threadIdx.x & 63;
    const int n    = lane & 15;   // lane owns out channels 2n, 2n+1
    const int quad = lane >> 4;

    // XCD-aware swizzle: contiguous 1/8th of voxel range per XCD
    int b   = blockIdx.x;
    int per = NBLOCKS / 8;
    int bs  = (b < per * 8) ? ((b & 7) * per + (b >> 3)) : b;
    int wv  = bs * WPB + (threadIdx.x >> 6);

    const int t0 = wv * TPW;
    if (t0 >= NTILES) return;     // (after the sync — safe)

    // ---- folded BN consts for this lane's channels (2n, 2n+1)
    f32x2 A_[3], B_[3];
    #pragma unroll
    for (int br = 0; br < 3; ++br) {
        A_[br] = *(const f32x2*)(wsA + br * 32 + 2 * n);
        B_[br] = *(const f32x2*)(wsB + br * 32 + 2 * n);
    }

    // ---- all neighbor indices for both tiles, loaded up-front
    int ip[TPW][3], inx[TPW][3];
    #pragma unroll
    for (int tt = 0; tt < TPW; ++tt) {
        int tile = t0 + tt;
        int row  = tile * 16 + n;
        if (tile < NTILES) {
            #pragma unroll
            for (int a = 0; a < 3; ++a) {
                ip[tt][a]  = nprev[a * NVOX + row];
                inx[tt][a] = nnext[a * NVOX + row];
            }
        } else {
            #pragma unroll
            for (int a = 0; a < 3; ++a) { ip[tt][a] = -1; inx[tt][a] = -1; }
        }
    }

    const u16x8* sWf = (const u16x8*)sW;   // frag f, lane l at [f*64 + l]

    #pragma unroll
    for (int tt = 0; tt < TPW; ++tt) {
        int tile = t0 + tt;
        if (tile >= NTILES) break;
        int base = tile * 16;
        int row  = base + n;

        // ---- branchless A loads: self + 6 gathers (clamped to self row)
        const f32x4* ps = (const f32x4*)(feat + row * 32 + quad * 8);
        f32x4 s_lo = ps[0], s_hi = ps[1];
        f32x4 p_lo[3], p_hi[3], n_lo[3], n_hi[3];
        #pragma unroll
        for (int a = 0; a < 3; ++a) {
            int rp = ip[tt][a]  >= 0 ? ip[tt][a]  : row;   // v_cndmask
            int rn = inx[tt][a] >= 0 ? inx[tt][a] : row;
            const f32x4* pp = (const f32x4*)(feat + rp * 32 + quad * 8);
            const f32x4* pn = (const f32x4*)(feat + rn * 32 + quad * 8);
            p_lo[a] = pp[0]; p_hi[a] = pp[1];
            n_lo[a] = pn[0]; n_hi[a] = pn[1];
        }

        // ---- convert + mask to bf16 fragments
        bf16x8 Aself = cvt_mask(s_lo, s_hi, true);
        bf16x8 Ap[3], An[3];
        #pragma unroll
        for (int a = 0; a < 3; ++a) {
            Ap[a] = cvt_mask(p_lo[a], p_hi[a], ip[tt][a]  >= 0);
            An[a] = cvt_mask(n_lo[a], n_hi[a], inx[tt][a] >= 0);
        }

        // ---- 3 branches x 6 MFMA (W frags streamed from LDS), sigmoid, sum
        f32x4 acc0 = {0.f, 0.f, 0.f, 0.f}, acc1 = {0.f, 0.f, 0.f, 0.f};
        #pragma unroll
        for (int br = 0; br < 3; ++br) {
            f32x4 c0 = {0.f, 0.f, 0.f, 0.f}, c1 = {0.f, 0.f, 0.f, 0.f};
            bf16x8 w0 = __builtin_bit_cast(bf16x8, sWf[(br*6 + 0) * 64 + lane]);
            bf16x8 w1 = __builtin_bit_cast(bf16x8, sWf[(br*6 + 1) * 64 + lane]);
            c0 = __builtin_amdgcn_mfma_f32_16x16x32_bf16(Ap[br], w0, c0, 0, 0, 0);
            c1 = __builtin_amdgcn_mfma_f32_16x16x32_bf16(Ap[br], w1, c1, 0, 0, 0);
            bf16x8 w2 = __builtin_bit_cast(bf16x8, sWf[(br*6 + 2) * 64 + lane]);
            bf16x8 w3 = __builtin_bit_cast(bf16x8, sWf[(br*6 + 3) * 64 + lane]);
            c0 = __builtin_amdgcn_mfma_f32_16x16x32_bf16(Aself,  w2, c0, 0, 0, 0);
            c1 = __builtin_amdgcn_mfma_f32_16x16x32_bf16(Aself,  w3, c1, 0, 0, 0);
            bf16x8 w4 = __builtin_bit_cast(bf16x8, sWf[(br*6 + 4) * 64 + lane]);
            bf16x8 w5 = __builtin_bit_cast(bf16x8, sWf[(br*6 + 5) * 64 + lane]);
            c0 = __builtin_amdgcn_mfma_f32_16x16x32_bf16(An[br], w4, c0, 0, 0, 0);
            c1 = __builtin_amdgcn_mfma_f32_16x16x32_bf16(An[br], w5, c1, 0, 0, 0);
            float a0 = A_[br][0], b0 = B_[br][0], a1 = A_[br][1], b1 = B_[br][1];
            #pragma unroll
            for (int r = 0; r < 4; ++r) {
                float e0 = __builtin_amdgcn_exp2f(__builtin_fmaf(c0[r], a0, b0));
                float e1 = __builtin_amdgcn_exp2f(__builtin_fmaf(c1[r], a1, b1));
                acc0[r] += __builtin_amdgcn_rcpf(1.0f + e0);
                acc1[r] += __builtin_amdgcn_rcpf(1.0f + e1);
            }
        }

        // ---- gate by input features and store (plain coalesced stores)
        #pragma unroll
        for (int r = 0; r < 4; ++r) {
            int vrow = base + quad * 4 + r;
            f32x2 fv = *(const f32x2*)(feat + vrow * 32 + 2 * n);
            f32x2 ov = { acc0[r] * fv[0], acc1[r] * fv[1] };
            *(f32x2*)(out + vrow * 32 + 2 * n) = ov;
        }
    }
}

extern "C" void kernel_launch(void* const* d_in, const int* in_sizes, int n_in,
                              void* d_out, int out_size, void* d_ws, size_t ws_size,
                              hipStream_t stream) {
    const float* feat  = (const float*)d_in[0];
    const int*   nprev = (const int*)d_in[1];
    const int*   nnext = (const int*)d_in[2];
    const float* Wt    = (const float*)d_in[3];
    const float* gma   = (const float*)d_in[4];
    const float* bta   = (const float*)d_in[5];
    const float* mea   = (const float*)d_in[6];
    const float* var   = (const float*)d_in[7];
    float*       o     = (float*)d_out;

    unsigned short* wsW = (unsigned short*)d_ws;
    float*          wsA = (float*)((char*)d_ws + WS_WELEMS * 2);
    float*          wsB = wsA + 96;

    prep_kernel<<<(WS_WELEMS + 96 + 255) / 256, 256, 0, stream>>>(
        Wt, gma, bta, mea, var, wsW, wsA, wsB);
    recon_kernel<<<NBLOCKS, 256, 0, stream>>>(feat, nprev, nnext,
                                              wsW, wsA, wsB, o);
}